// Round 8
// baseline (188.102 us; speedup 1.0000x reference)
//
#include <hip/hip_runtime.h>
#include <hip/hip_fp16.h>

#define CH 64
#define NBUCK 1024        // buckets = dst >> 7 (128 nodes/bucket); needs N <= 131072
#define BSHIFT 7
#define BMASK 127
#define NBLK_P 512        // partition blocks; must match k_hist/k_partition/k_bucketscan
#define RPMASK 0x1FFFFFu  // packed row_ptr: start in [0:21), deg in [21:32)

typedef _Float16 f16x4 __attribute__((ext_vector_type(4)));
typedef float    f32x4 __attribute__((ext_vector_type(4)));

// ---- CSR build: scatter-free two-level bucket sort ------------------------
// (R5 lesson: global-atomic scatter = 122us from 64B-line write-amplification
//  across XCD L2s; LDS-bucketed two-pass sort keeps scatters bucket-local.)

// k_hist also absorbs the old k_init (block 0: wt fold + W1 frag pack) --
// hidden under the other 511 blocks' histogram work; saves a serial launch.
__global__ __launch_bounds__(256) void k_hist(const int* __restrict__ dst,
                                              int* __restrict__ blkhist, int E,
                                              const float* __restrict__ W2,
                                              const float* __restrict__ Wl,
                                              float* __restrict__ wt,
                                              const float* __restrict__ W1,
                                              __half* __restrict__ wfrag) {
    __shared__ int h[NBUCK];
    for (int i = threadIdx.x; i < NBUCK; i += blockDim.x) h[i] = 0;
    __syncthreads();
    int chunk = (E + NBLK_P - 1) / NBLK_P;
    int beg = blockIdx.x * chunk;
    int end = min(beg + chunk, E);
    for (int e = beg + threadIdx.x; e < end; e += blockDim.x)
        atomicAdd(&h[dst[e] >> BSHIFT], 1);
    __syncthreads();
    for (int i = threadIdx.x; i < NBUCK; i += blockDim.x)
        blkhist[blockIdx.x * NBUCK + i] = h[i];

    if (blockIdx.x == 0) {
        if (threadIdx.x < 64) {
            int k = threadIdx.x;
            float s = 0.0f;
#pragma unroll 8
            for (int c = 0; c < CH; ++c) s = fmaf(W2[k * CH + c], Wl[c], s);
            wt[k] = s;
        }
        for (int idx = threadIdx.x; idx < 1024; idx += 256) {
            int f = idx >> 6;
            int l = idx & 63;
            int w4 = f >> 2, t = f & 3;
            int kb = w4 * 16 + 4 * (l >> 4);
            int c  = t * 16 + (l & 15);
#pragma unroll
            for (int b = 0; b < 4; ++b) {
                float wv = W1[(kb + b) * CH + c];
                __half hi = __float2half(wv);
                float lo = wv - __half2float(hi);
                wfrag[(size_t)f * 256 + l * 4 + b] = hi;
                wfrag[4096 + (size_t)f * 256 + l * 4 + b] = __float2half(lo);
            }
        }
    }
}

// One wave per bucket: scan blkhist[b][t] along b (512 values, 8/lane).
__global__ __launch_bounds__(256) void k_bucketscan(const int* __restrict__ blkhist,
                                                    int* __restrict__ off_t,
                                                    int* __restrict__ tot) {
    int lane = threadIdx.x & 63;
    int t = (blockIdx.x * blockDim.x + threadIdx.x) >> 6;   // bucket id 0..1023
    int v[8], pre[8];
    int sum = 0;
#pragma unroll
    for (int j = 0; j < 8; ++j) {
        v[j] = blkhist[(lane * 8 + j) * NBUCK + t];
        pre[j] = sum;
        sum += v[j];
    }
    int sc = sum;
#pragma unroll
    for (int o = 1; o < 64; o <<= 1) {
        int u = __shfl_up(sc, o, 64);
        if (lane >= o) sc += u;
    }
    int excl = sc - sum;
#pragma unroll
    for (int j = 0; j < 8; ++j)
        off_t[t * NBLK_P + lane * 8 + j] = excl + pre[j];
    if (lane == 63) tot[t] = sc;
}

// k_partition computes bbase locally (LDS scan of the 1024 tot values, 4KB
// L2-hot, ~1us hidden across 512 parallel blocks) -- replaces k_scantot.
__global__ __launch_bounds__(256) void k_partition(const int* __restrict__ src,
                                                   const int* __restrict__ dst,
                                                   const int* __restrict__ off_t,
                                                   const int* __restrict__ tot,
                                                   unsigned int* __restrict__ ebuf, int E) {
    __shared__ int cur[NBUCK];
    __shared__ int psum[256];
    int t = threadIdx.x;
    int b = blockIdx.x;
    int4 tv = *(const int4*)(tot + 4 * t);
    int s = tv.x + tv.y + tv.z + tv.w;
    psum[t] = s;
    __syncthreads();
    for (int o = 1; o < 256; o <<= 1) {
        int u = (t >= o) ? psum[t - o] : 0;
        __syncthreads();
        psum[t] += u;
        __syncthreads();
    }
    int base = psum[t] - s;   // exclusive bucket base for bucket 4t
    cur[4 * t + 0] = base                       + off_t[(4 * t + 0) * NBLK_P + b];
    cur[4 * t + 1] = base + tv.x                + off_t[(4 * t + 1) * NBLK_P + b];
    cur[4 * t + 2] = base + tv.x + tv.y         + off_t[(4 * t + 2) * NBLK_P + b];
    cur[4 * t + 3] = base + tv.x + tv.y + tv.z  + off_t[(4 * t + 3) * NBLK_P + b];
    __syncthreads();
    int chunk = (E + NBLK_P - 1) / NBLK_P;
    int beg = b * chunk;
    int end = min(beg + chunk, E);
    for (int e = beg + threadIdx.x; e < end; e += blockDim.x) {
        int sv = src[e];
        int d = dst[e];
        int p = atomicAdd(&cur[d >> BSHIFT], 1);
        ebuf[p] = ((unsigned int)(d & BMASK) << 17) | (unsigned int)sv;
    }
}

// Compact CSR: col holds exactly the edges (no self, no pads).
// row_ptr[node] = start | (deg << 21).  start < E=1.6M < 2^21; deg < 2^11.
// 512 threads: edge loops (count + scatter) 2x wider than R7; e0 computed
// locally as reduce(tot[0..k)) -- no bbase array needed.
__global__ __launch_bounds__(512) void k_bucket_csr(const unsigned int* __restrict__ ebuf,
                                                    const int* __restrict__ tot,
                                                    int* __restrict__ row_ptr,
                                                    float* __restrict__ dinv,
                                                    int* __restrict__ col, int n) {
    __shared__ int cnt[128];
    __shared__ int cur[128];
    __shared__ int sc[128];
    __shared__ int rsum[512];
    int t = threadIdx.x;
    int k = blockIdx.x;
    int part = 0;
    for (int i = t; i < k; i += 512) part += tot[i];
    rsum[t] = part;
    if (t < 128) cnt[t] = 0;
    __syncthreads();
    for (int o = 256; o > 0; o >>= 1) {
        if (t < o) rsum[t] += rsum[t + o];
        __syncthreads();
    }
    int e0 = rsum[0];
    int e1 = e0 + tot[k];
    for (int e = e0 + t; e < e1; e += 512)
        atomicAdd(&cnt[ebuf[e] >> 17], 1);
    __syncthreads();
    int c = 0;
    if (t < 128) { c = cnt[t]; sc[t] = c; }
    __syncthreads();
    for (int o = 1; o < 128; o <<= 1) {
        int v = (t >= o && t < 128) ? sc[t - o] : 0;
        __syncthreads();
        if (t < 128) sc[t] += v;
        __syncthreads();
    }
    if (t < 128) {
        int excl = sc[t] - c;
        int prow = e0 + excl;
        int node = (k << BSHIFT) + t;
        if (node < n) {
            row_ptr[node] = prow | (c << 21);
            dinv[node] = rsqrtf((float)(c + 1));   // +1 self-loop
        }
        cur[t] = prow;
    }
    __syncthreads();
    for (int e = e0 + t; e < e1; e += 512) {
        unsigned int u = ebuf[e];
        int p = atomicAdd(&cur[u >> 17], 1);
        col[p] = (int)(u & 0x1FFFFu);
    }
}

// ---- Layer-1 GEMM via MFMA: hs = (x @ W1) * dinv, fp16 out ----------------
// Wave handles 16 nodes x 64 cols: 4 k-windows x 4 col-tiles.
// fp16 hi/lo split (xh@Wh + xl@Wh + xh@Wl) keeps fp32-level accuracy; f32 acc.

__global__ __launch_bounds__(256) void k_gemm_mfma(const float* __restrict__ in,
                                                   const __half* __restrict__ wfrag,
                                                   const float* __restrict__ dinv,
                                                   __half* __restrict__ hs, int n) {
    if (blockIdx.x == 0 && threadIdx.x < CH)
        hs[(size_t)n * CH + threadIdx.x] = __float2half(0.0f);   // zero row (pads)

    int lane = threadIdx.x & 63;
    int wid  = (blockIdx.x * blockDim.x + threadIdx.x) >> 6;
    int nw   = (gridDim.x * blockDim.x) >> 6;

    const f16x4* wf = (const f16x4*)wfrag;
    f16x4 wh[16], wl[16];
#pragma unroll
    for (int f = 0; f < 16; ++f) {
        wh[f] = wf[f * 64 + lane];
        wl[f] = wf[1024 + f * 64 + lane];
    }

    int r15 = lane & 15;
    int q   = lane >> 4;
    int ngrp = (n + 15) >> 4;

    for (int g = wid; g < ngrp; g += nw) {
        int base = g << 4;
        int arow = min(base + r15, n - 1);
        const float* ap = in + (size_t)arow * CH + 4 * q;

        f32x4 acc0 = {0.f, 0.f, 0.f, 0.f};
        f32x4 acc1 = {0.f, 0.f, 0.f, 0.f};
        f32x4 acc2 = {0.f, 0.f, 0.f, 0.f};
        f32x4 acc3 = {0.f, 0.f, 0.f, 0.f};

#pragma unroll
        for (int w4 = 0; w4 < 4; ++w4) {
            float4 xv = *(const float4*)(ap + w4 * 16);
            f16x4 ah, al;
            ah[0] = (_Float16)xv.x; al[0] = (_Float16)(xv.x - (float)ah[0]);
            ah[1] = (_Float16)xv.y; al[1] = (_Float16)(xv.y - (float)ah[1]);
            ah[2] = (_Float16)xv.z; al[2] = (_Float16)(xv.z - (float)ah[2]);
            ah[3] = (_Float16)xv.w; al[3] = (_Float16)(xv.w - (float)ah[3]);

            acc0 = __builtin_amdgcn_mfma_f32_16x16x16f16(ah, wh[w4 * 4 + 0], acc0, 0, 0, 0);
            acc1 = __builtin_amdgcn_mfma_f32_16x16x16f16(ah, wh[w4 * 4 + 1], acc1, 0, 0, 0);
            acc2 = __builtin_amdgcn_mfma_f32_16x16x16f16(ah, wh[w4 * 4 + 2], acc2, 0, 0, 0);
            acc3 = __builtin_amdgcn_mfma_f32_16x16x16f16(ah, wh[w4 * 4 + 3], acc3, 0, 0, 0);
            acc0 = __builtin_amdgcn_mfma_f32_16x16x16f16(al, wh[w4 * 4 + 0], acc0, 0, 0, 0);
            acc1 = __builtin_amdgcn_mfma_f32_16x16x16f16(al, wh[w4 * 4 + 1], acc1, 0, 0, 0);
            acc2 = __builtin_amdgcn_mfma_f32_16x16x16f16(al, wh[w4 * 4 + 2], acc2, 0, 0, 0);
            acc3 = __builtin_amdgcn_mfma_f32_16x16x16f16(al, wh[w4 * 4 + 3], acc3, 0, 0, 0);
            acc0 = __builtin_amdgcn_mfma_f32_16x16x16f16(ah, wl[w4 * 4 + 0], acc0, 0, 0, 0);
            acc1 = __builtin_amdgcn_mfma_f32_16x16x16f16(ah, wl[w4 * 4 + 1], acc1, 0, 0, 0);
            acc2 = __builtin_amdgcn_mfma_f32_16x16x16f16(ah, wl[w4 * 4 + 2], acc2, 0, 0, 0);
            acc3 = __builtin_amdgcn_mfma_f32_16x16x16f16(ah, wl[w4 * 4 + 3], acc3, 0, 0, 0);
        }

#pragma unroll
        for (int b = 0; b < 4; ++b) {
            int row = base + 4 * q + b;
            if (row < n) {
                float d = dinv[row];
                size_t o = (size_t)row * CH + r15;
                hs[o +  0] = __float2half(acc0[b] * d);
                hs[o + 16] = __float2half(acc1[b] * d);
                hs[o + 32] = __float2half(acc2[b] * d);
                hs[o + 48] = __float2half(acc3[b] * d);
            }
        }
    }
}

// ---- fused: gather(agg1) + bias + relu + dot(w~) -> z ---------------------
// v4 tiling: 16B loads. Half-wave g owns node (a+g). lane = rg*8 + lg;
// lg owns channels 8lg..8lg+7 (one 16B slice); rg owns rows == rg (mod 4).
// One wave-wide load fetches FOUR rows. Self-loop folded into slot r == deg.
// Pads hit L1-hot row n. Epilogue: shfl_xor(8,16) row-subset reduce ->
// per-lane 8-ch relu/dot -> shfl_xor(1,2,4).

__global__ __launch_bounds__(256) void k_gather_gemm(const int* __restrict__ row_ptr,
                                                     const int* __restrict__ col,
                                                     const __half2* __restrict__ hs2,
                                                     const float* __restrict__ dinv,
                                                     const float* __restrict__ wt,
                                                     const float* __restrict__ bias,
                                                     float* __restrict__ z, int n) {
    int lane = threadIdx.x & 63;
    int l    = lane & 31;
    int g    = lane >> 5;          // half-wave: 0 -> node a, 1 -> node b
    int lg   = l & 7;              // channel-slice: f16 channels 8lg..8lg+7
    int rg   = l >> 3;             // row-subset: rows == rg (mod 4)
    int wid  = (blockIdx.x * blockDim.x + threadIdx.x) >> 6;
    int nw   = (gridDim.x * blockDim.x) >> 6;

    float4 bi0 = ((const float4*)bias)[2 * lg];
    float4 bi1 = ((const float4*)bias)[2 * lg + 1];
    float4 wt0 = ((const float4*)wt)[2 * lg];
    float4 wt1 = ((const float4*)wt)[2 * lg + 1];

    int npairs = (n + 1) >> 1;
    int pr = wid;
    if (pr >= npairs) return;

    unsigned pkA = (unsigned)row_ptr[pr << 1];
    unsigned pkB = (unsigned)row_ptr[min((pr << 1) + 1, n - 1)];
    int cv = col[(int)((g ? pkB : pkA) & RPMASK) + l];

    for (; pr < npairs; pr += nw) {
        int a = pr << 1;
        bool hasB = (a + 1) < n;
        int begS = (int)((g ? pkB : pkA) & RPMASK);
        int degS = (int)((g ? pkB : pkA) >> 21);
        int degA = (int)(pkA >> 21), degB = (int)(pkB >> 21);
        int selfS = g ? (hasB ? a + 1 : a) : a;
        int mycv = cv;
        float dA = dinv[a];
        float dB = dinv[hasB ? a + 1 : a];

        // 8 x 16B loads in flight: load i fetches rows 4i..4i+3 (this half)
        float4 raw[8];
#pragma unroll
        for (int i = 0; i < 8; ++i) {
            int r = 4 * i + rg;
            int cr = __shfl(mycv, r, 32);
            int idx = (r < degS) ? cr : ((r == degS) ? selfS : n);
            raw[i] = *(const float4*)(hs2 + ((size_t)idx << 5) + (lg << 2));
        }

        // prefetch next pair header + col vector (hidden under accumulate)
        int nxt = pr + nw;
        if (nxt < npairs) {
            int a1 = nxt << 1;
            pkA = (unsigned)row_ptr[a1];
            pkB = (unsigned)row_ptr[min(a1 + 1, n - 1)];
            cv = col[(int)((g ? pkB : pkA) & RPMASK) + l];
        }

        // accumulate: 4 half2-slots -> 4 float2 accumulators (8 channels)
        float2 a0 = make_float2(0.f, 0.f), a1 = make_float2(0.f, 0.f);
        float2 a2 = make_float2(0.f, 0.f), a3 = make_float2(0.f, 0.f);
#pragma unroll
        for (int i = 0; i < 8; ++i) {
            const __half2* hp = (const __half2*)&raw[i];
            float2 f0 = __half22float2(hp[0]);
            float2 f1 = __half22float2(hp[1]);
            float2 f2 = __half22float2(hp[2]);
            float2 f3 = __half22float2(hp[3]);
            a0.x += f0.x; a0.y += f0.y;
            a1.x += f1.x; a1.y += f1.y;
            a2.x += f2.x; a2.y += f2.y;
            a3.x += f3.x; a3.y += f3.y;
        }

        if (max(degA, degB) >= 32) {        // heavy nodes + the deg==32 self slot
            for (int r = 32 + rg; r <= degS; r += 4) {
                int idx = (r < degS) ? col[begS + r] : selfS;
                float4 rv = *(const float4*)(hs2 + ((size_t)idx << 5) + (lg << 2));
                const __half2* hp = (const __half2*)&rv;
                float2 f0 = __half22float2(hp[0]);
                float2 f1 = __half22float2(hp[1]);
                float2 f2 = __half22float2(hp[2]);
                float2 f3 = __half22float2(hp[3]);
                a0.x += f0.x; a0.y += f0.y;
                a1.x += f1.x; a1.y += f1.y;
                a2.x += f2.x; a2.y += f2.y;
                a3.x += f3.x; a3.y += f3.y;
            }
        }

        // reduce the 4 row-subsets (lanes rg=0..3 of each lg column)
        a0.x += __shfl_xor(a0.x, 8, 64);  a0.y += __shfl_xor(a0.y, 8, 64);
        a1.x += __shfl_xor(a1.x, 8, 64);  a1.y += __shfl_xor(a1.y, 8, 64);
        a2.x += __shfl_xor(a2.x, 8, 64);  a2.y += __shfl_xor(a2.y, 8, 64);
        a3.x += __shfl_xor(a3.x, 8, 64);  a3.y += __shfl_xor(a3.y, 8, 64);
        a0.x += __shfl_xor(a0.x, 16, 64); a0.y += __shfl_xor(a0.y, 16, 64);
        a1.x += __shfl_xor(a1.x, 16, 64); a1.y += __shfl_xor(a1.y, 16, 64);
        a2.x += __shfl_xor(a2.x, 16, 64); a2.y += __shfl_xor(a2.y, 16, 64);
        a3.x += __shfl_xor(a3.x, 16, 64); a3.y += __shfl_xor(a3.y, 16, 64);

        float d = g ? dB : dA;
        float p;
        {
            float v;
            v = fmaxf(fmaf(a0.x, d, bi0.x), 0.0f); p  = v * wt0.x;
            v = fmaxf(fmaf(a0.y, d, bi0.y), 0.0f); p = fmaf(v, wt0.y, p);
            v = fmaxf(fmaf(a1.x, d, bi0.z), 0.0f); p = fmaf(v, wt0.z, p);
            v = fmaxf(fmaf(a1.y, d, bi0.w), 0.0f); p = fmaf(v, wt0.w, p);
            v = fmaxf(fmaf(a2.x, d, bi1.x), 0.0f); p = fmaf(v, wt1.x, p);
            v = fmaxf(fmaf(a2.y, d, bi1.y), 0.0f); p = fmaf(v, wt1.y, p);
            v = fmaxf(fmaf(a3.x, d, bi1.z), 0.0f); p = fmaf(v, wt1.z, p);
            v = fmaxf(fmaf(a3.y, d, bi1.w), 0.0f); p = fmaf(v, wt1.w, p);
        }
        // all 4 row-groups hold identical channel sums -> reduce only 8 lanes
        p += __shfl_xor(p, 1, 64);
        p += __shfl_xor(p, 2, 64);
        p += __shfl_xor(p, 4, 64);
        p *= d;
        if (l == 0 && (g == 0 || hasB)) z[a + g] = p;
    }
}

// ---- head: out[n] = sigmoid(dinv[n]*(z[n]+sum z[s]) + (b2.Wl + bl)) -------
// v3: 8 threads per node (2 edges each at avg deg 16), 3-hop shfl_xor reduce
// within the aligned 8-lane group.

__global__ __launch_bounds__(256) void k_head(const int* __restrict__ row_ptr,
                                              const int* __restrict__ col,
                                              const float* __restrict__ z,
                                              const float* __restrict__ dinv,
                                              const float* __restrict__ b2,
                                              const float* __restrict__ Wl,
                                              const float* __restrict__ bl,
                                              float* __restrict__ out, int n) {
    int lane = threadIdx.x & 63;
    float c0 = b2[lane] * Wl[lane];
#pragma unroll
    for (int o = 32; o > 0; o >>= 1) c0 += __shfl_xor(c0, o, 64);
    c0 += bl[0];

    int tid = blockIdx.x * blockDim.x + threadIdx.x;
    int st  = gridDim.x * blockDim.x;
    int n8  = n << 3;
    for (int q = tid; q < n8; q += st) {
        int node = q >> 3;
        int sub  = q & 7;
        unsigned pk = (unsigned)row_ptr[node];
        int beg = (int)(pk & RPMASK);
        int deg = (int)(pk >> 21);
        float s = (sub == 0) ? z[node] : 0.0f;
        for (int e = sub; e < deg; e += 8) s += z[col[beg + e]];
        s += __shfl_xor(s, 1, 64);
        s += __shfl_xor(s, 2, 64);
        s += __shfl_xor(s, 4, 64);
        if (sub == 0) {
            float v = dinv[node] * s + c0;
            out[node] = 1.0f / (1.0f + expf(-v));
        }
    }
}

// ---- launch ---------------------------------------------------------------

extern "C" void kernel_launch(void* const* d_in, const int* in_sizes, int n_in,
                              void* d_out, int out_size, void* d_ws, size_t ws_size,
                              hipStream_t stream) {
    const float* x   = (const float*)d_in[0];
    const int*   ei  = (const int*)d_in[1];   // [2, E] row-major
    const float* W1  = (const float*)d_in[2];
    const float* b1  = (const float*)d_in[3];
    const float* W2  = (const float*)d_in[4];
    const float* b2  = (const float*)d_in[5];
    const float* Wl  = (const float*)d_in[6];
    const float* bl  = (const float*)d_in[7];
    float*       out = (float*)d_out;

    const int N = in_sizes[0] / CH;
    const int E = in_sizes[1] / 2;
    const int* src = ei;
    const int* dst = ei + E;

    const size_t Npad = ((size_t)N + 511) & ~(size_t)511;
    const size_t Epad = ((size_t)E + 511) & ~(size_t)511;
    const size_t COLSZ = Epad + 512;          // compact CSR (+ slack for OOB-safe reads)

    // Persistent region:
    float* z        = (float*)d_ws;                   // Npad
    float* dinv     = z + Npad;                       // Npad
    int*   row_ptr  = (int*)(dinv + Npad);            // Npad (packed start|deg<<21)
    float* wt       = (float*)(row_ptr + Npad);       // 512 slot (w~ = W2@Wl)
    __half* wfrag   = (__half*)(wt + 512);            // 8192 halves (W1 hi/lo frags)
    int*   col      = (int*)(wfrag + 8192);           // COLSZ
    // Transient region (dead after k_bucket_csr) — later aliased by A:
    unsigned int* ebuf = (unsigned int*)(col + COLSZ);   // Epad
    int*   blkhist  = (int*)(ebuf + Epad);            // NBLK_P*NBUCK (2 MB)
    int*   off_t    = blkhist + (size_t)NBLK_P * NBUCK; // NBUCK*NBLK_P (2 MB)
    int*   tot      = off_t + (size_t)NBLK_P * NBUCK; // NBUCK (16B-aligned)
    // A ((N+1) rows fp16, row n zeroed) aliases the transient region:
    __half* A       = (__half*)ebuf;

    const int TB = 256;
    const int GRID = 2048;
    const int NB_USED = (N + BMASK) >> BSHIFT;

    // CSR build — scatter-free, no single-block serial stages
    k_hist<<<NBLK_P, TB, 0, stream>>>(dst, blkhist, E, W2, Wl, wt, W1, wfrag);
    k_bucketscan<<<NBUCK * 64 / TB, TB, 0, stream>>>(blkhist, off_t, tot);
    k_partition<<<NBLK_P, TB, 0, stream>>>(src, dst, off_t, tot, ebuf, E);
    k_bucket_csr<<<NB_USED, 512, 0, stream>>>(ebuf, tot, row_ptr, dinv, col, N);

    // Layer 1: A = (x @ W1) * dinv  (fp16, MFMA)  [A overwrites dead ebuf region]
    k_gemm_mfma<<<784, TB, 0, stream>>>(x, wfrag, dinv, A, N);

    // Layer 2 fused: gather(A) -> relu(agg1+b1) . w~ -> z
    k_gather_gemm<<<2 * GRID, TB, 0, stream>>>(row_ptr, col, (const __half2*)A, dinv,
                                               wt, b1, z, N);

    // Head: 8-threads-per-node gather over z + sigmoid
    k_head<<<((N << 3) + TB - 1) / TB, TB, 0, stream>>>(row_ptr, col, z, dinv,
                                                        b2, Wl, bl, out, N);
}

// Round 9
// 184.987 us; speedup vs baseline: 1.0168x; 1.0168x over previous
//
#include <hip/hip_runtime.h>
#include <hip/hip_fp16.h>

#define CH 64
#define NBUCK 1024        // buckets = dst >> 7 (128 nodes/bucket); needs N <= 131072
#define BSHIFT 7
#define BMASK 127
#define NBLK_P 512        // partition blocks; must match k_hist/k_partition/k_bucketscan
#define RPMASK 0x1FFFFFu  // packed row_ptr: start in [0:21), deg in [21:32)

typedef _Float16 f16x4 __attribute__((ext_vector_type(4)));
typedef float    f32x4 __attribute__((ext_vector_type(4)));

// ---- CSR build: scatter-free two-level bucket sort ------------------------
// (R5 lesson: global-atomic scatter = 122us from 64B-line write-amplification
//  across XCD L2s; LDS-bucketed two-pass sort keeps scatters bucket-local.)

// k_hist also absorbs the old k_init (block 0: wt fold + W1 frag pack) --
// hidden under the other 511 blocks' histogram work; saves a serial launch.
__global__ __launch_bounds__(256) void k_hist(const int* __restrict__ dst,
                                              int* __restrict__ blkhist, int E,
                                              const float* __restrict__ W2,
                                              const float* __restrict__ Wl,
                                              float* __restrict__ wt,
                                              const float* __restrict__ W1,
                                              __half* __restrict__ wfrag) {
    __shared__ int h[NBUCK];
    for (int i = threadIdx.x; i < NBUCK; i += blockDim.x) h[i] = 0;
    __syncthreads();
    int chunk = (E + NBLK_P - 1) / NBLK_P;
    int beg = blockIdx.x * chunk;
    int end = min(beg + chunk, E);
    for (int e = beg + threadIdx.x; e < end; e += blockDim.x)
        atomicAdd(&h[dst[e] >> BSHIFT], 1);
    __syncthreads();
    for (int i = threadIdx.x; i < NBUCK; i += blockDim.x)
        blkhist[blockIdx.x * NBUCK + i] = h[i];

    if (blockIdx.x == 0) {
        if (threadIdx.x < 64) {
            int k = threadIdx.x;
            float s = 0.0f;
#pragma unroll 8
            for (int c = 0; c < CH; ++c) s = fmaf(W2[k * CH + c], Wl[c], s);
            wt[k] = s;
        }
        for (int idx = threadIdx.x; idx < 1024; idx += 256) {
            int f = idx >> 6;
            int l = idx & 63;
            int w4 = f >> 2, t = f & 3;
            int kb = w4 * 16 + 4 * (l >> 4);
            int c  = t * 16 + (l & 15);
#pragma unroll
            for (int b = 0; b < 4; ++b) {
                float wv = W1[(kb + b) * CH + c];
                __half hi = __float2half(wv);
                float lo = wv - __half2float(hi);
                wfrag[(size_t)f * 256 + l * 4 + b] = hi;
                wfrag[4096 + (size_t)f * 256 + l * 4 + b] = __float2half(lo);
            }
        }
    }
}

// One wave per bucket: scan blkhist[b][t] along b (512 values, 8/lane).
__global__ __launch_bounds__(256) void k_bucketscan(const int* __restrict__ blkhist,
                                                    int* __restrict__ off_t,
                                                    int* __restrict__ tot) {
    int lane = threadIdx.x & 63;
    int t = (blockIdx.x * blockDim.x + threadIdx.x) >> 6;   // bucket id 0..1023
    int v[8], pre[8];
    int sum = 0;
#pragma unroll
    for (int j = 0; j < 8; ++j) {
        v[j] = blkhist[(lane * 8 + j) * NBUCK + t];
        pre[j] = sum;
        sum += v[j];
    }
    int sc = sum;
#pragma unroll
    for (int o = 1; o < 64; o <<= 1) {
        int u = __shfl_up(sc, o, 64);
        if (lane >= o) sc += u;
    }
    int excl = sc - sum;
#pragma unroll
    for (int j = 0; j < 8; ++j)
        off_t[t * NBLK_P + lane * 8 + j] = excl + pre[j];
    if (lane == 63) tot[t] = sc;
}

// k_partition computes bucket bases locally (LDS scan of the 1024 tot values,
// 4KB L2-hot, hidden across 512 parallel blocks) -- replaces k_scantot.
// Block 0 additionally WRITES bbase out for k_bucket_csr (free: it already
// has the scan in LDS; avoids R8's per-block tot-reduce in k_bucket_csr).
__global__ __launch_bounds__(256) void k_partition(const int* __restrict__ src,
                                                   const int* __restrict__ dst,
                                                   const int* __restrict__ off_t,
                                                   const int* __restrict__ tot,
                                                   int* __restrict__ bbase,
                                                   unsigned int* __restrict__ ebuf, int E) {
    __shared__ int cur[NBUCK];
    __shared__ int psum[256];
    int t = threadIdx.x;
    int b = blockIdx.x;
    int4 tv = *(const int4*)(tot + 4 * t);
    int s = tv.x + tv.y + tv.z + tv.w;
    psum[t] = s;
    __syncthreads();
    for (int o = 1; o < 256; o <<= 1) {
        int u = (t >= o) ? psum[t - o] : 0;
        __syncthreads();
        psum[t] += u;
        __syncthreads();
    }
    int base = psum[t] - s;   // exclusive bucket base for bucket 4t
    int b0 = base;
    int b1 = base + tv.x;
    int b2 = b1 + tv.y;
    int b3 = b2 + tv.z;
    cur[4 * t + 0] = b0 + off_t[(4 * t + 0) * NBLK_P + b];
    cur[4 * t + 1] = b1 + off_t[(4 * t + 1) * NBLK_P + b];
    cur[4 * t + 2] = b2 + off_t[(4 * t + 2) * NBLK_P + b];
    cur[4 * t + 3] = b3 + off_t[(4 * t + 3) * NBLK_P + b];
    if (b == 0) {
        ((int4*)bbase)[t] = make_int4(b0, b1, b2, b3);
        if (t == 255) bbase[NBUCK] = psum[255];
    }
    __syncthreads();
    int chunk = (E + NBLK_P - 1) / NBLK_P;
    int beg = b * chunk;
    int end = min(beg + chunk, E);
    for (int e = beg + threadIdx.x; e < end; e += blockDim.x) {
        int sv = src[e];
        int d = dst[e];
        int p = atomicAdd(&cur[d >> BSHIFT], 1);
        ebuf[p] = ((unsigned int)(d & BMASK) << 17) | (unsigned int)sv;
    }
}

// Compact CSR: col holds exactly the edges (no self, no pads).
// row_ptr[node] = start | (deg << 21).  start < E=1.6M < 2^21; deg < 2^11.
// 512 threads: edge loops (count + scatter) run wide; bucket range from bbase.
__global__ __launch_bounds__(512) void k_bucket_csr(const unsigned int* __restrict__ ebuf,
                                                    const int* __restrict__ bbase,
                                                    int* __restrict__ row_ptr,
                                                    float* __restrict__ dinv,
                                                    int* __restrict__ col, int n) {
    __shared__ int cnt[128];
    __shared__ int cur[128];
    __shared__ int sc[128];
    int t = threadIdx.x;
    int k = blockIdx.x;
    int e0 = bbase[k], e1 = bbase[k + 1];
    if (t < 128) cnt[t] = 0;
    __syncthreads();
    for (int e = e0 + t; e < e1; e += 512)
        atomicAdd(&cnt[ebuf[e] >> 17], 1);
    __syncthreads();
    int c = 0;
    if (t < 128) { c = cnt[t]; sc[t] = c; }
    __syncthreads();
    for (int o = 1; o < 128; o <<= 1) {
        int v = (t >= o && t < 128) ? sc[t - o] : 0;
        __syncthreads();
        if (t < 128) sc[t] += v;
        __syncthreads();
    }
    if (t < 128) {
        int excl = sc[t] - c;
        int prow = e0 + excl;
        int node = (k << BSHIFT) + t;
        if (node < n) {
            row_ptr[node] = prow | (c << 21);
            dinv[node] = rsqrtf((float)(c + 1));   // +1 self-loop
        }
        cur[t] = prow;
    }
    __syncthreads();
    for (int e = e0 + t; e < e1; e += 512) {
        unsigned int u = ebuf[e];
        int p = atomicAdd(&cur[u >> 17], 1);
        col[p] = (int)(u & 0x1FFFFu);
    }
}

// ---- Layer-1 GEMM via MFMA: hs = (x @ W1) * dinv, fp16 out ----------------
// Wave handles 16 nodes x 64 cols: 4 k-windows x 4 col-tiles.
// fp16 hi/lo split (xh@Wh + xl@Wh + xh@Wl) keeps fp32-level accuracy; f32 acc.

__global__ __launch_bounds__(256) void k_gemm_mfma(const float* __restrict__ in,
                                                   const __half* __restrict__ wfrag,
                                                   const float* __restrict__ dinv,
                                                   __half* __restrict__ hs, int n) {
    if (blockIdx.x == 0 && threadIdx.x < CH)
        hs[(size_t)n * CH + threadIdx.x] = __float2half(0.0f);   // zero row (pads)

    int lane = threadIdx.x & 63;
    int wid  = (blockIdx.x * blockDim.x + threadIdx.x) >> 6;
    int nw   = (gridDim.x * blockDim.x) >> 6;

    const f16x4* wf = (const f16x4*)wfrag;
    f16x4 wh[16], wl[16];
#pragma unroll
    for (int f = 0; f < 16; ++f) {
        wh[f] = wf[f * 64 + lane];
        wl[f] = wf[1024 + f * 64 + lane];
    }

    int r15 = lane & 15;
    int q   = lane >> 4;
    int ngrp = (n + 15) >> 4;

    for (int g = wid; g < ngrp; g += nw) {
        int base = g << 4;
        int arow = min(base + r15, n - 1);
        const float* ap = in + (size_t)arow * CH + 4 * q;

        f32x4 acc0 = {0.f, 0.f, 0.f, 0.f};
        f32x4 acc1 = {0.f, 0.f, 0.f, 0.f};
        f32x4 acc2 = {0.f, 0.f, 0.f, 0.f};
        f32x4 acc3 = {0.f, 0.f, 0.f, 0.f};

#pragma unroll
        for (int w4 = 0; w4 < 4; ++w4) {
            float4 xv = *(const float4*)(ap + w4 * 16);
            f16x4 ah, al;
            ah[0] = (_Float16)xv.x; al[0] = (_Float16)(xv.x - (float)ah[0]);
            ah[1] = (_Float16)xv.y; al[1] = (_Float16)(xv.y - (float)ah[1]);
            ah[2] = (_Float16)xv.z; al[2] = (_Float16)(xv.z - (float)ah[2]);
            ah[3] = (_Float16)xv.w; al[3] = (_Float16)(xv.w - (float)ah[3]);

            acc0 = __builtin_amdgcn_mfma_f32_16x16x16f16(ah, wh[w4 * 4 + 0], acc0, 0, 0, 0);
            acc1 = __builtin_amdgcn_mfma_f32_16x16x16f16(ah, wh[w4 * 4 + 1], acc1, 0, 0, 0);
            acc2 = __builtin_amdgcn_mfma_f32_16x16x16f16(ah, wh[w4 * 4 + 2], acc2, 0, 0, 0);
            acc3 = __builtin_amdgcn_mfma_f32_16x16x16f16(ah, wh[w4 * 4 + 3], acc3, 0, 0, 0);
            acc0 = __builtin_amdgcn_mfma_f32_16x16x16f16(al, wh[w4 * 4 + 0], acc0, 0, 0, 0);
            acc1 = __builtin_amdgcn_mfma_f32_16x16x16f16(al, wh[w4 * 4 + 1], acc1, 0, 0, 0);
            acc2 = __builtin_amdgcn_mfma_f32_16x16x16f16(al, wh[w4 * 4 + 2], acc2, 0, 0, 0);
            acc3 = __builtin_amdgcn_mfma_f32_16x16x16f16(al, wh[w4 * 4 + 3], acc3, 0, 0, 0);
            acc0 = __builtin_amdgcn_mfma_f32_16x16x16f16(ah, wl[w4 * 4 + 0], acc0, 0, 0, 0);
            acc1 = __builtin_amdgcn_mfma_f32_16x16x16f16(ah, wl[w4 * 4 + 1], acc1, 0, 0, 0);
            acc2 = __builtin_amdgcn_mfma_f32_16x16x16f16(ah, wl[w4 * 4 + 2], acc2, 0, 0, 0);
            acc3 = __builtin_amdgcn_mfma_f32_16x16x16f16(ah, wl[w4 * 4 + 3], acc3, 0, 0, 0);
        }

#pragma unroll
        for (int b = 0; b < 4; ++b) {
            int row = base + 4 * q + b;
            if (row < n) {
                float d = dinv[row];
                size_t o = (size_t)row * CH + r15;
                hs[o +  0] = __float2half(acc0[b] * d);
                hs[o + 16] = __float2half(acc1[b] * d);
                hs[o + 32] = __float2half(acc2[b] * d);
                hs[o + 48] = __float2half(acc3[b] * d);
            }
        }
    }
}

// ---- fused: gather(agg1) + bias + relu + dot(w~) -> z ---------------------
// v4 tiling: 16B loads. Half-wave g owns node (a+g). lane = rg*8 + lg;
// lg owns channels 8lg..8lg+7 (one 16B slice); rg owns rows == rg (mod 4).
// One wave-wide load fetches FOUR rows. Self-loop folded into slot r == deg.
// Pads hit L1-hot row n. Epilogue: shfl_xor(8,16) row-subset reduce ->
// per-lane 8-ch relu/dot -> shfl_xor(1,2,4).

__global__ __launch_bounds__(256) void k_gather_gemm(const int* __restrict__ row_ptr,
                                                     const int* __restrict__ col,
                                                     const __half2* __restrict__ hs2,
                                                     const float* __restrict__ dinv,
                                                     const float* __restrict__ wt,
                                                     const float* __restrict__ bias,
                                                     float* __restrict__ z, int n) {
    int lane = threadIdx.x & 63;
    int l    = lane & 31;
    int g    = lane >> 5;          // half-wave: 0 -> node a, 1 -> node b
    int lg   = l & 7;              // channel-slice: f16 channels 8lg..8lg+7
    int rg   = l >> 3;             // row-subset: rows == rg (mod 4)
    int wid  = (blockIdx.x * blockDim.x + threadIdx.x) >> 6;
    int nw   = (gridDim.x * blockDim.x) >> 6;

    float4 bi0 = ((const float4*)bias)[2 * lg];
    float4 bi1 = ((const float4*)bias)[2 * lg + 1];
    float4 wt0 = ((const float4*)wt)[2 * lg];
    float4 wt1 = ((const float4*)wt)[2 * lg + 1];

    int npairs = (n + 1) >> 1;
    int pr = wid;
    if (pr >= npairs) return;

    unsigned pkA = (unsigned)row_ptr[pr << 1];
    unsigned pkB = (unsigned)row_ptr[min((pr << 1) + 1, n - 1)];
    int cv = col[(int)((g ? pkB : pkA) & RPMASK) + l];

    for (; pr < npairs; pr += nw) {
        int a = pr << 1;
        bool hasB = (a + 1) < n;
        int begS = (int)((g ? pkB : pkA) & RPMASK);
        int degS = (int)((g ? pkB : pkA) >> 21);
        int degA = (int)(pkA >> 21), degB = (int)(pkB >> 21);
        int selfS = g ? (hasB ? a + 1 : a) : a;
        int mycv = cv;
        float dA = dinv[a];
        float dB = dinv[hasB ? a + 1 : a];

        // 8 x 16B loads in flight: load i fetches rows 4i..4i+3 (this half)
        float4 raw[8];
#pragma unroll
        for (int i = 0; i < 8; ++i) {
            int r = 4 * i + rg;
            int cr = __shfl(mycv, r, 32);
            int idx = (r < degS) ? cr : ((r == degS) ? selfS : n);
            raw[i] = *(const float4*)(hs2 + ((size_t)idx << 5) + (lg << 2));
        }

        // prefetch next pair header + col vector (hidden under accumulate)
        int nxt = pr + nw;
        if (nxt < npairs) {
            int a1 = nxt << 1;
            pkA = (unsigned)row_ptr[a1];
            pkB = (unsigned)row_ptr[min(a1 + 1, n - 1)];
            cv = col[(int)((g ? pkB : pkA) & RPMASK) + l];
        }

        // accumulate: 4 half2-slots -> 4 float2 accumulators (8 channels)
        float2 a0 = make_float2(0.f, 0.f), a1 = make_float2(0.f, 0.f);
        float2 a2 = make_float2(0.f, 0.f), a3 = make_float2(0.f, 0.f);
#pragma unroll
        for (int i = 0; i < 8; ++i) {
            const __half2* hp = (const __half2*)&raw[i];
            float2 f0 = __half22float2(hp[0]);
            float2 f1 = __half22float2(hp[1]);
            float2 f2 = __half22float2(hp[2]);
            float2 f3 = __half22float2(hp[3]);
            a0.x += f0.x; a0.y += f0.y;
            a1.x += f1.x; a1.y += f1.y;
            a2.x += f2.x; a2.y += f2.y;
            a3.x += f3.x; a3.y += f3.y;
        }

        if (max(degA, degB) >= 32) {        // heavy nodes + the deg==32 self slot
            for (int r = 32 + rg; r <= degS; r += 4) {
                int idx = (r < degS) ? col[begS + r] : selfS;
                float4 rv = *(const float4*)(hs2 + ((size_t)idx << 5) + (lg << 2));
                const __half2* hp = (const __half2*)&rv;
                float2 f0 = __half22float2(hp[0]);
                float2 f1 = __half22float2(hp[1]);
                float2 f2 = __half22float2(hp[2]);
                float2 f3 = __half22float2(hp[3]);
                a0.x += f0.x; a0.y += f0.y;
                a1.x += f1.x; a1.y += f1.y;
                a2.x += f2.x; a2.y += f2.y;
                a3.x += f3.x; a3.y += f3.y;
            }
        }

        // reduce the 4 row-subsets (lanes rg=0..3 of each lg column)
        a0.x += __shfl_xor(a0.x, 8, 64);  a0.y += __shfl_xor(a0.y, 8, 64);
        a1.x += __shfl_xor(a1.x, 8, 64);  a1.y += __shfl_xor(a1.y, 8, 64);
        a2.x += __shfl_xor(a2.x, 8, 64);  a2.y += __shfl_xor(a2.y, 8, 64);
        a3.x += __shfl_xor(a3.x, 8, 64);  a3.y += __shfl_xor(a3.y, 8, 64);
        a0.x += __shfl_xor(a0.x, 16, 64); a0.y += __shfl_xor(a0.y, 16, 64);
        a1.x += __shfl_xor(a1.x, 16, 64); a1.y += __shfl_xor(a1.y, 16, 64);
        a2.x += __shfl_xor(a2.x, 16, 64); a2.y += __shfl_xor(a2.y, 16, 64);
        a3.x += __shfl_xor(a3.x, 16, 64); a3.y += __shfl_xor(a3.y, 16, 64);

        float d = g ? dB : dA;
        float p;
        {
            float v;
            v = fmaxf(fmaf(a0.x, d, bi0.x), 0.0f); p  = v * wt0.x;
            v = fmaxf(fmaf(a0.y, d, bi0.y), 0.0f); p = fmaf(v, wt0.y, p);
            v = fmaxf(fmaf(a1.x, d, bi0.z), 0.0f); p = fmaf(v, wt0.z, p);
            v = fmaxf(fmaf(a1.y, d, bi0.w), 0.0f); p = fmaf(v, wt0.w, p);
            v = fmaxf(fmaf(a2.x, d, bi1.x), 0.0f); p = fmaf(v, wt1.x, p);
            v = fmaxf(fmaf(a2.y, d, bi1.y), 0.0f); p = fmaf(v, wt1.y, p);
            v = fmaxf(fmaf(a3.x, d, bi1.z), 0.0f); p = fmaf(v, wt1.z, p);
            v = fmaxf(fmaf(a3.y, d, bi1.w), 0.0f); p = fmaf(v, wt1.w, p);
        }
        // all 4 row-groups hold identical channel sums -> reduce only 8 lanes
        p += __shfl_xor(p, 1, 64);
        p += __shfl_xor(p, 2, 64);
        p += __shfl_xor(p, 4, 64);
        p *= d;
        if (l == 0 && (g == 0 || hasB)) z[a + g] = p;
    }
}

// ---- head: out[n] = sigmoid(dinv[n]*(z[n]+sum z[s]) + (b2.Wl + bl)) -------
// 8 threads per node (2 edges each at avg deg 16), 3-hop shfl_xor reduce
// within the aligned 8-lane group.

__global__ __launch_bounds__(256) void k_head(const int* __restrict__ row_ptr,
                                              const int* __restrict__ col,
                                              const float* __restrict__ z,
                                              const float* __restrict__ dinv,
                                              const float* __restrict__ b2,
                                              const float* __restrict__ Wl,
                                              const float* __restrict__ bl,
                                              float* __restrict__ out, int n) {
    int lane = threadIdx.x & 63;
    float c0 = b2[lane] * Wl[lane];
#pragma unroll
    for (int o = 32; o > 0; o >>= 1) c0 += __shfl_xor(c0, o, 64);
    c0 += bl[0];

    int tid = blockIdx.x * blockDim.x + threadIdx.x;
    int st  = gridDim.x * blockDim.x;
    int n8  = n << 3;
    for (int q = tid; q < n8; q += st) {
        int node = q >> 3;
        int sub  = q & 7;
        unsigned pk = (unsigned)row_ptr[node];
        int beg = (int)(pk & RPMASK);
        int deg = (int)(pk >> 21);
        float s = (sub == 0) ? z[node] : 0.0f;
        for (int e = sub; e < deg; e += 8) s += z[col[beg + e]];
        s += __shfl_xor(s, 1, 64);
        s += __shfl_xor(s, 2, 64);
        s += __shfl_xor(s, 4, 64);
        if (sub == 0) {
            float v = dinv[node] * s + c0;
            out[node] = 1.0f / (1.0f + expf(-v));
        }
    }
}

// ---- launch ---------------------------------------------------------------

extern "C" void kernel_launch(void* const* d_in, const int* in_sizes, int n_in,
                              void* d_out, int out_size, void* d_ws, size_t ws_size,
                              hipStream_t stream) {
    const float* x   = (const float*)d_in[0];
    const int*   ei  = (const int*)d_in[1];   // [2, E] row-major
    const float* W1  = (const float*)d_in[2];
    const float* b1  = (const float*)d_in[3];
    const float* W2  = (const float*)d_in[4];
    const float* b2  = (const float*)d_in[5];
    const float* Wl  = (const float*)d_in[6];
    const float* bl  = (const float*)d_in[7];
    float*       out = (float*)d_out;

    const int N = in_sizes[0] / CH;
    const int E = in_sizes[1] / 2;
    const int* src = ei;
    const int* dst = ei + E;

    const size_t Npad = ((size_t)N + 511) & ~(size_t)511;
    const size_t Epad = ((size_t)E + 511) & ~(size_t)511;
    const size_t COLSZ = Epad + 512;          // compact CSR (+ slack for OOB-safe reads)

    // Persistent region:
    float* z        = (float*)d_ws;                   // Npad
    float* dinv     = z + Npad;                       // Npad
    int*   row_ptr  = (int*)(dinv + Npad);            // Npad (packed start|deg<<21)
    float* wt       = (float*)(row_ptr + Npad);       // 512 slot (w~ = W2@Wl)
    __half* wfrag   = (__half*)(wt + 512);            // 8192 halves (W1 hi/lo frags)
    int*   col      = (int*)(wfrag + 8192);           // COLSZ
    // Transient region (dead after k_bucket_csr) — later aliased by A:
    unsigned int* ebuf = (unsigned int*)(col + COLSZ);   // Epad
    int*   blkhist  = (int*)(ebuf + Epad);            // NBLK_P*NBUCK (2 MB)
    int*   off_t    = blkhist + (size_t)NBLK_P * NBUCK; // NBUCK*NBLK_P (2 MB)
    int*   tot      = off_t + (size_t)NBLK_P * NBUCK; // NBUCK (16B-aligned)
    int*   bbase    = tot + NBUCK;                    // NBUCK+1 (+pad, 16B-aligned)
    // A ((N+1) rows fp16, row n zeroed) aliases the transient region:
    __half* A       = (__half*)ebuf;

    const int TB = 256;
    const int GRID = 2048;
    const int NB_USED = (N + BMASK) >> BSHIFT;

    // CSR build — scatter-free, no single-block serial stages
    k_hist<<<NBLK_P, TB, 0, stream>>>(dst, blkhist, E, W2, Wl, wt, W1, wfrag);
    k_bucketscan<<<NBUCK * 64 / TB, TB, 0, stream>>>(blkhist, off_t, tot);
    k_partition<<<NBLK_P, TB, 0, stream>>>(src, dst, off_t, tot, bbase, ebuf, E);
    k_bucket_csr<<<NB_USED, 512, 0, stream>>>(ebuf, bbase, row_ptr, dinv, col, N);

    // Layer 1: A = (x @ W1) * dinv  (fp16, MFMA)  [A overwrites dead ebuf region]
    k_gemm_mfma<<<784, TB, 0, stream>>>(x, wfrag, dinv, A, N);

    // Layer 2 fused: gather(A) -> relu(agg1+b1) . w~ -> z
    k_gather_gemm<<<2 * GRID, TB, 0, stream>>>(row_ptr, col, (const __half2*)A, dinv,
                                               wt, b1, z, N);

    // Head: 8-threads-per-node gather over z + sigmoid
    k_head<<<((N << 3) + TB - 1) / TB, TB, 0, stream>>>(row_ptr, col, z, dinv,
                                                        b2, Wl, bl, out, N);
}